// Round 6
// baseline (265.120 us; speedup 1.0000x reference)
//
#include <hip/hip_runtime.h>

// GIN 2-layer forward, f32 — CSR two-level counting sort + deep-batched gathers.
// Pipeline:
//   bin_hist -> scan_bins -> partition -> bin_finalize        (CSR by dst)
//   agg1 = x + gather(x)             [gather64, 8-deep MLP batch]
//   h    = relu(agg1 @ W1 + b1)      [gemm1_relu, 16 rows/block]
//   g    = h @ W2                    [gemm2]
//   out  = g + b2 + gather(g)        [gather64, 8-deep]
// (W2 folded before aggregation-2: (A h + h) W2 + b2 = A(hW2) + hW2 + b2.)
// Round-5 lesson: fusing gather into the GEMM block cost occupancy (41% vs 65%)
// and the latency-bound gather phase lost more MLP than the fusion saved in HBM.

#define EPB 4096     // edges per block in bin_hist / partition
#define CAP 6144     // LDS staging cap for bin_finalize

__global__ __launch_bounds__(256) void bin_hist(const int* __restrict__ dst,
                                                int* __restrict__ binCnt, int ne, int nbins) {
    __shared__ int h[512];
    int t = threadIdx.x;
    for (int i = t; i < nbins; i += 256) h[i] = 0;
    __syncthreads();
    int eb = blockIdx.x * EPB;
#pragma unroll
    for (int i = 0; i < 16; ++i) {
        int e = eb + t + i * 256;
        if (e < ne) atomicAdd(&h[dst[e] >> 8], 1);
    }
    __syncthreads();
    for (int i = t; i < nbins; i += 256) if (h[i]) atomicAdd(&binCnt[i], h[i]);
}

__global__ __launch_bounds__(512) void scan_bins(const int* __restrict__ binCnt,
                                                 int* __restrict__ binOff, int* __restrict__ binCur,
                                                 int* __restrict__ off, int nbins, int n, int ne) {
    __shared__ int s[512];
    int t = threadIdx.x;
    int v = (t < nbins) ? binCnt[t] : 0;
    s[t] = v;
    __syncthreads();
    for (int o = 1; o < 512; o <<= 1) {
        int u = (t >= o) ? s[t - o] : 0;
        __syncthreads();
        s[t] += u;
        __syncthreads();
    }
    if (t < nbins) { int b = s[t] - v; binOff[t] = b; binCur[t] = b; }
    if (t == 0) { binOff[nbins] = ne; off[n] = ne; }
}

__global__ __launch_bounds__(256) void partition(const int* __restrict__ src,
                                                 const int* __restrict__ dst,
                                                 int* __restrict__ binCur,
                                                 unsigned* __restrict__ part, int ne, int nbins) {
    __shared__ int h[512];
    __shared__ int base[512];
    int t = threadIdx.x;
    for (int i = t; i < nbins; i += 256) h[i] = 0;
    __syncthreads();
    int eb = blockIdx.x * EPB;
    int ss[16], ds[16];
#pragma unroll
    for (int i = 0; i < 16; ++i) {
        int e = eb + t + i * 256;
        if (e < ne) { ss[i] = src[e]; ds[i] = dst[e]; atomicAdd(&h[ds[i] >> 8], 1); }
        else ds[i] = -1;
    }
    __syncthreads();
    for (int i = t; i < nbins; i += 256) base[i] = h[i] ? atomicAdd(&binCur[i], h[i]) : 0;
    __syncthreads();
    for (int i = t; i < nbins; i += 256) h[i] = 0;
    __syncthreads();
#pragma unroll
    for (int i = 0; i < 16; ++i) {
        if (ds[i] >= 0) {
            int b = ds[i] >> 8;
            int p = atomicAdd(&h[b], 1);
            part[base[b] + p] = ((unsigned)ss[i] << 8) | (unsigned)(ds[i] & 255);
        }
    }
}

__global__ __launch_bounds__(256) void bin_finalize(const unsigned* __restrict__ part,
                                                    const int* __restrict__ binOff,
                                                    int* __restrict__ off, int* __restrict__ perm,
                                                    int n, int nbins) {
    __shared__ unsigned st[CAP];
    __shared__ int cnt[256], ex[256], cur[256];
    int b = blockIdx.x;
    int t = threadIdx.x;
    int e0 = binOff[b], e1 = binOff[b + 1];
    int m = e1 - e0;
    int nb0 = b << 8;
    int nn = min(256, n - nb0);
    cnt[t] = 0;
    __syncthreads();
    bool staged = (m <= CAP);
    if (staged) {
        for (int i = t; i < m; i += 256) { unsigned v = part[e0 + i]; st[i] = v; atomicAdd(&cnt[v & 255u], 1); }
    } else {
        for (int i = t; i < m; i += 256) { unsigned v = part[e0 + i]; atomicAdd(&cnt[v & 255u], 1); }
    }
    __syncthreads();
    int v = cnt[t];
    ex[t] = v;
    __syncthreads();
    for (int o = 1; o < 256; o <<= 1) {
        int u = (t >= o) ? ex[t - o] : 0;
        __syncthreads();
        ex[t] += u;
        __syncthreads();
    }
    int excl = ex[t] - v;
    if (t < nn) off[nb0 + t] = e0 + excl;
    cur[t] = excl;
    __syncthreads();
    if (staged) {
        for (int i = t; i < m; i += 256) {
            unsigned w = st[i];
            int p = atomicAdd(&cur[w & 255u], 1);
            perm[e0 + p] = (int)(w >> 8);
        }
    } else {
        for (int i = t; i < m; i += 256) {
            unsigned w = part[e0 + i];
            int p = atomicAdd(&cur[w & 255u], 1);
            perm[e0 + p] = (int)(w >> 8);
        }
    }
}

// out[i] = x[i] (+ bias) + sum_{e in CSR(i)} x[perm[e]]
// 16 threads/node, 16 nodes/block, 8-deep edge batch for MLP.
__global__ __launch_bounds__(256) void gather64(const float4* __restrict__ x4,
                                                const int* __restrict__ off,
                                                const int* __restrict__ perm,
                                                const float* __restrict__ bias,
                                                float4* __restrict__ out4, int n) {
    int t = threadIdx.x;
    int node = blockIdx.x * 16 + (t >> 4);
    int c = t & 15;
    if (node >= n) return;
    int beg = off[node], end = off[node + 1];
    float4 acc = x4[(size_t)node * 16 + c];
    int e = beg;
    for (; e + 8 <= end; e += 8) {
        int s0 = perm[e],     s1 = perm[e + 1], s2 = perm[e + 2], s3 = perm[e + 3];
        int s4 = perm[e + 4], s5 = perm[e + 5], s6 = perm[e + 6], s7 = perm[e + 7];
        float4 v0 = x4[(size_t)s0 * 16 + c];
        float4 v1 = x4[(size_t)s1 * 16 + c];
        float4 v2 = x4[(size_t)s2 * 16 + c];
        float4 v3 = x4[(size_t)s3 * 16 + c];
        float4 v4 = x4[(size_t)s4 * 16 + c];
        float4 v5 = x4[(size_t)s5 * 16 + c];
        float4 v6 = x4[(size_t)s6 * 16 + c];
        float4 v7 = x4[(size_t)s7 * 16 + c];
        acc.x += ((v0.x + v1.x) + (v2.x + v3.x)) + ((v4.x + v5.x) + (v6.x + v7.x));
        acc.y += ((v0.y + v1.y) + (v2.y + v3.y)) + ((v4.y + v5.y) + (v6.y + v7.y));
        acc.z += ((v0.z + v1.z) + (v2.z + v3.z)) + ((v4.z + v5.z) + (v6.z + v7.z));
        acc.w += ((v0.w + v1.w) + (v2.w + v3.w)) + ((v4.w + v5.w) + (v6.w + v7.w));
    }
    for (; e + 4 <= end; e += 4) {
        int s0 = perm[e], s1 = perm[e + 1], s2 = perm[e + 2], s3 = perm[e + 3];
        float4 v0 = x4[(size_t)s0 * 16 + c];
        float4 v1 = x4[(size_t)s1 * 16 + c];
        float4 v2 = x4[(size_t)s2 * 16 + c];
        float4 v3 = x4[(size_t)s3 * 16 + c];
        acc.x += (v0.x + v1.x) + (v2.x + v3.x);
        acc.y += (v0.y + v1.y) + (v2.y + v3.y);
        acc.z += (v0.z + v1.z) + (v2.z + v3.z);
        acc.w += (v0.w + v1.w) + (v2.w + v3.w);
    }
    for (; e < end; ++e) {
        int s = perm[e];
        float4 v = x4[(size_t)s * 16 + c];
        acc.x += v.x; acc.y += v.y; acc.z += v.z; acc.w += v.w;
    }
    if (bias) {
        float4 bb = reinterpret_cast<const float4*>(bias)[c];
        acc.x += bb.x; acc.y += bb.y; acc.z += bb.z; acc.w += bb.w;
    }
    out4[(size_t)node * 16 + c] = acc;
}

// h[n,128] = relu(x[n,64] @ W1[64,128] + b1); 16 rows/block (n % 16 == 0)
__global__ __launch_bounds__(256) void gemm1_relu(const float* __restrict__ x,
                                                  const float* __restrict__ W1,
                                                  const float* __restrict__ b1,
                                                  float* __restrict__ h, int n) {
    __shared__ float4 Ws[64][32];   // 32 KiB
    __shared__ float  xs[16][68];   // 4.25 KiB
    int t = threadIdx.x;
    const float4* W4 = reinterpret_cast<const float4*>(W1);
    for (int i = t; i < 64 * 32; i += 256) Ws[i >> 5][i & 31] = W4[i];

    int row0 = blockIdx.x * 16;
    const float4* x4 = reinterpret_cast<const float4*>(x + (size_t)row0 * 64);
    {   // stage 16 rows x 64 f32 = 256 float4, one per thread
        float4 v = x4[t];
        int r = t >> 4, cc = t & 15;
        xs[r][cc * 4 + 0] = v.x;
        xs[r][cc * 4 + 1] = v.y;
        xs[r][cc * 4 + 2] = v.z;
        xs[r][cc * 4 + 3] = v.w;
    }
    __syncthreads();

    int r = t >> 4;   // 0..15
    int c = t & 15;   // col groups c and c+16
    float4 a0 = {0.f, 0.f, 0.f, 0.f}, a1 = {0.f, 0.f, 0.f, 0.f};
#pragma unroll
    for (int k = 0; k < 64; ++k) {
        float a = xs[r][k];
        float4 w0 = Ws[k][c];
        float4 w1 = Ws[k][c + 16];
        a0.x += a * w0.x; a0.y += a * w0.y; a0.z += a * w0.z; a0.w += a * w0.w;
        a1.x += a * w1.x; a1.y += a * w1.y; a1.z += a * w1.z; a1.w += a * w1.w;
    }
    const float4* b4 = reinterpret_cast<const float4*>(b1);
    float4 q0 = b4[c], q1 = b4[c + 16];
    a0.x = fmaxf(a0.x + q0.x, 0.f); a0.y = fmaxf(a0.y + q0.y, 0.f);
    a0.z = fmaxf(a0.z + q0.z, 0.f); a0.w = fmaxf(a0.w + q0.w, 0.f);
    a1.x = fmaxf(a1.x + q1.x, 0.f); a1.y = fmaxf(a1.y + q1.y, 0.f);
    a1.z = fmaxf(a1.z + q1.z, 0.f); a1.w = fmaxf(a1.w + q1.w, 0.f);
    float4* h4 = reinterpret_cast<float4*>(h) + ((size_t)row0 + r) * 32;
    h4[c] = a0;
    h4[c + 16] = a1;
}

// g[n,64] = h[n,128] @ W2[128,64]; 16 rows/block
__global__ __launch_bounds__(256) void gemm2(const float* __restrict__ h,
                                             const float* __restrict__ W2,
                                             float* __restrict__ g, int n) {
    __shared__ float4 Ws[128][16];
    __shared__ float  xs[16][132];
    int t = threadIdx.x;
    const float4* W4 = reinterpret_cast<const float4*>(W2);
    for (int i = t; i < 128 * 16; i += 256) Ws[i >> 4][i & 15] = W4[i];
    int row0 = blockIdx.x * 16;
    const float4* x4 = reinterpret_cast<const float4*>(h + (size_t)row0 * 128);
    for (int i = t; i < 512; i += 256) {
        int r = i >> 5, c = i & 31;
        *reinterpret_cast<float4*>(&xs[r][c * 4]) = x4[i];
    }
    __syncthreads();

    int row = t >> 4;
    int cg  = t & 15;
    float4 acc = {0.f, 0.f, 0.f, 0.f};
#pragma unroll
    for (int k = 0; k < 128; ++k) {
        float a = xs[row][k];
        float4 w = Ws[k][cg];
        acc.x += a * w.x; acc.y += a * w.y; acc.z += a * w.z; acc.w += a * w.w;
    }
    reinterpret_cast<float4*>(g)[(size_t)(row0 + row) * 16 + cg] = acc;
}

extern "C" void kernel_launch(void* const* d_in, const int* in_sizes, int n_in,
                              void* d_out, int out_size, void* d_ws, size_t ws_size,
                              hipStream_t stream) {
    const float* node_emb = (const float*)d_in[0];
    const float* W1 = (const float*)d_in[1];
    const float* b1 = (const float*)d_in[2];
    const float* W2 = (const float*)d_in[3];
    const float* b2 = (const float*)d_in[4];
    const int*   ei = (const int*)d_in[5];
    int n  = in_sizes[0] / 64;
    int ne = in_sizes[5] / 2;
    const int* src = ei;
    const int* dst = ei + ne;
    float* out = (float*)d_out;

    int nbins = (n + 255) >> 8;   // 391

    // workspace layout (part aliases h: part is dead before gemm1 writes h)
    char* ws = (char*)d_ws;
    float* agg1 = (float*)ws;                                  // n*64 f32, reused as g
    float* h    = (float*)(ws + (size_t)n * 64 * 4);           // n*128 f32
    unsigned* part = (unsigned*)h;                             // ne u32 (alias, dead by gemm1)
    char*  p    = ws + (size_t)n * 64 * 4 + (size_t)n * 128 * 4;
    int* off    = (int*)p;            p += (size_t)(n + 1) * 4;
    int* perm   = (int*)p;            p += (size_t)ne * 4;
    int* binCnt = (int*)p;            p += (size_t)(nbins + 1) * 4;
    int* binOff = (int*)p;            p += (size_t)(nbins + 1) * 4;
    int* binCur = (int*)p;            p += (size_t)(nbins + 1) * 4;
    float* g = agg1;                                           // agg1 dead after gemm1

    int nblk = (ne + EPB - 1) / EPB;   // 391

    hipMemsetAsync(binCnt, 0, (size_t)nbins * 4, stream);
    bin_hist<<<nblk, 256, 0, stream>>>(dst, binCnt, ne, nbins);
    scan_bins<<<1, 512, 0, stream>>>(binCnt, binOff, binCur, off, nbins, n, ne);
    partition<<<nblk, 256, 0, stream>>>(src, dst, binCur, part, ne, nbins);
    bin_finalize<<<nbins, 256, 0, stream>>>(part, binOff, off, perm, n, nbins);

    gather64<<<(n + 15) / 16, 256, 0, stream>>>((const float4*)node_emb, off, perm,
                                                nullptr, (float4*)agg1, n);
    gemm1_relu<<<(n + 15) / 16, 256, 0, stream>>>(agg1, W1, b1, h, n);
    gemm2<<<(n + 15) / 16, 256, 0, stream>>>(h, W2, g, n);
    gather64<<<(n + 15) / 16, 256, 0, stream>>>((const float4*)g, off, perm,
                                                b2, (float4*)out, n);
}

// Round 7
// 227.222 us; speedup vs baseline: 1.1668x; 1.1668x over previous
//
#include <hip/hip_runtime.h>

// GIN 2-layer forward — CSR counting sort + bf16 neighbor-gather tables.
// Pipeline:
//   cvt_bf16: xh = bf16(node_emb)                       (12.8 MB table)
//   bin_hist -> scan_bins -> partition -> bin_finalize  (CSR by dst)
//   agg1 = x + gather_bf16(xh)        [gather64h, 8-deep]
//   h    = relu(agg1 @ W1 + b1)       [gemm1_relu]
//   gemm2: gh = bf16(h @ W2); out = h@W2 + b2           (f32 self+bias in out)
//   out += gather_bf16(gh)            [gather64h, 8-deep]
// (W2 folded before aggregation-2: (A h + h) W2 + b2 = A(hW2) + hW2 + b2.)
// Round-6 lesson: gather is cache-hierarchy-throughput-bound (8-deep batching
// only gave 72->60.5us). bf16 payload halves the dominant byte stream.

#define EPB 4096
#define CAP 6144

__device__ __forceinline__ unsigned short f2b(float f) {   // RNE f32->bf16
    unsigned u = __float_as_uint(f);
    return (unsigned short)((u + 0x7fffu + ((u >> 16) & 1u)) >> 16);
}
__device__ __forceinline__ unsigned pk(float a, float b) {
    return (unsigned)f2b(a) | ((unsigned)f2b(b) << 16);
}
__device__ __forceinline__ float bl(unsigned u) { return __uint_as_float(u << 16); }
__device__ __forceinline__ float bh(unsigned u) { return __uint_as_float(u & 0xffff0000u); }

__global__ void cvt_bf16(const float4* __restrict__ x4, uint2* __restrict__ xh, int n16) {
    int i = blockIdx.x * blockDim.x + threadIdx.x;
    if (i >= n16) return;
    float4 v = x4[i];
    xh[i] = make_uint2(pk(v.x, v.y), pk(v.z, v.w));
}

__global__ __launch_bounds__(256) void bin_hist(const int* __restrict__ dst,
                                                int* __restrict__ binCnt, int ne, int nbins) {
    __shared__ int h[512];
    int t = threadIdx.x;
    for (int i = t; i < nbins; i += 256) h[i] = 0;
    __syncthreads();
    int eb = blockIdx.x * EPB;
#pragma unroll
    for (int i = 0; i < 16; ++i) {
        int e = eb + t + i * 256;
        if (e < ne) atomicAdd(&h[dst[e] >> 8], 1);
    }
    __syncthreads();
    for (int i = t; i < nbins; i += 256) if (h[i]) atomicAdd(&binCnt[i], h[i]);
}

__global__ __launch_bounds__(512) void scan_bins(const int* __restrict__ binCnt,
                                                 int* __restrict__ binOff, int* __restrict__ binCur,
                                                 int* __restrict__ off, int nbins, int n, int ne) {
    __shared__ int s[512];
    int t = threadIdx.x;
    int v = (t < nbins) ? binCnt[t] : 0;
    s[t] = v;
    __syncthreads();
    for (int o = 1; o < 512; o <<= 1) {
        int u = (t >= o) ? s[t - o] : 0;
        __syncthreads();
        s[t] += u;
        __syncthreads();
    }
    if (t < nbins) { int b = s[t] - v; binOff[t] = b; binCur[t] = b; }
    if (t == 0) { binOff[nbins] = ne; off[n] = ne; }
}

__global__ __launch_bounds__(256) void partition(const int* __restrict__ src,
                                                 const int* __restrict__ dst,
                                                 int* __restrict__ binCur,
                                                 unsigned* __restrict__ part, int ne, int nbins) {
    __shared__ int h[512];
    __shared__ int base[512];
    int t = threadIdx.x;
    for (int i = t; i < nbins; i += 256) h[i] = 0;
    __syncthreads();
    int eb = blockIdx.x * EPB;
    int ss[16], ds[16];
#pragma unroll
    for (int i = 0; i < 16; ++i) {
        int e = eb + t + i * 256;
        if (e < ne) { ss[i] = src[e]; ds[i] = dst[e]; atomicAdd(&h[ds[i] >> 8], 1); }
        else ds[i] = -1;
    }
    __syncthreads();
    for (int i = t; i < nbins; i += 256) base[i] = h[i] ? atomicAdd(&binCur[i], h[i]) : 0;
    __syncthreads();
    for (int i = t; i < nbins; i += 256) h[i] = 0;
    __syncthreads();
#pragma unroll
    for (int i = 0; i < 16; ++i) {
        if (ds[i] >= 0) {
            int b = ds[i] >> 8;
            int p = atomicAdd(&h[b], 1);
            part[base[b] + p] = ((unsigned)ss[i] << 8) | (unsigned)(ds[i] & 255);
        }
    }
}

__global__ __launch_bounds__(256) void bin_finalize(const unsigned* __restrict__ part,
                                                    const int* __restrict__ binOff,
                                                    int* __restrict__ off, int* __restrict__ perm,
                                                    int n, int nbins) {
    __shared__ unsigned st[CAP];
    __shared__ int cnt[256], ex[256], cur[256];
    int b = blockIdx.x;
    int t = threadIdx.x;
    int e0 = binOff[b], e1 = binOff[b + 1];
    int m = e1 - e0;
    int nb0 = b << 8;
    int nn = min(256, n - nb0);
    cnt[t] = 0;
    __syncthreads();
    bool staged = (m <= CAP);
    if (staged) {
        for (int i = t; i < m; i += 256) { unsigned v = part[e0 + i]; st[i] = v; atomicAdd(&cnt[v & 255u], 1); }
    } else {
        for (int i = t; i < m; i += 256) { unsigned v = part[e0 + i]; atomicAdd(&cnt[v & 255u], 1); }
    }
    __syncthreads();
    int v = cnt[t];
    ex[t] = v;
    __syncthreads();
    for (int o = 1; o < 256; o <<= 1) {
        int u = (t >= o) ? ex[t - o] : 0;
        __syncthreads();
        ex[t] += u;
        __syncthreads();
    }
    int excl = ex[t] - v;
    if (t < nn) off[nb0 + t] = e0 + excl;
    cur[t] = excl;
    __syncthreads();
    if (staged) {
        for (int i = t; i < m; i += 256) {
            unsigned w = st[i];
            int p = atomicAdd(&cur[w & 255u], 1);
            perm[e0 + p] = (int)(w >> 8);
        }
    } else {
        for (int i = t; i < m; i += 256) {
            unsigned w = part[e0 + i];
            int p = atomicAdd(&cur[w & 255u], 1);
            perm[e0 + p] = (int)(w >> 8);
        }
    }
}

// out[i] = selfSrc[i] + sum_{e in CSR(i)} bf16_table[perm[e]]
// 16 threads/node, 16 nodes/block, 8-deep edge batch. Neighbor rows are
// 128 B (uint2/lane = 4 bf16 channels). selfSrc may alias out (per-thread
// read-then-write of the same element only).
__global__ __launch_bounds__(256) void gather64h(const uint2* __restrict__ xh,
                                                 const float4* selfSrc,
                                                 const int* __restrict__ off,
                                                 const int* __restrict__ perm,
                                                 float4* out4, int n) {
    int t = threadIdx.x;
    int node = blockIdx.x * 16 + (t >> 4);
    int c = t & 15;
    if (node >= n) return;
    int beg = off[node], end = off[node + 1];
    float4 acc = selfSrc[(size_t)node * 16 + c];
    int e = beg;
    for (; e + 8 <= end; e += 8) {
        int s0 = perm[e],     s1 = perm[e + 1], s2 = perm[e + 2], s3 = perm[e + 3];
        int s4 = perm[e + 4], s5 = perm[e + 5], s6 = perm[e + 6], s7 = perm[e + 7];
        uint2 v0 = xh[(size_t)s0 * 16 + c];
        uint2 v1 = xh[(size_t)s1 * 16 + c];
        uint2 v2 = xh[(size_t)s2 * 16 + c];
        uint2 v3 = xh[(size_t)s3 * 16 + c];
        uint2 v4 = xh[(size_t)s4 * 16 + c];
        uint2 v5 = xh[(size_t)s5 * 16 + c];
        uint2 v6 = xh[(size_t)s6 * 16 + c];
        uint2 v7 = xh[(size_t)s7 * 16 + c];
        acc.x += ((bl(v0.x) + bl(v1.x)) + (bl(v2.x) + bl(v3.x))) +
                 ((bl(v4.x) + bl(v5.x)) + (bl(v6.x) + bl(v7.x)));
        acc.y += ((bh(v0.x) + bh(v1.x)) + (bh(v2.x) + bh(v3.x))) +
                 ((bh(v4.x) + bh(v5.x)) + (bh(v6.x) + bh(v7.x)));
        acc.z += ((bl(v0.y) + bl(v1.y)) + (bl(v2.y) + bl(v3.y))) +
                 ((bl(v4.y) + bl(v5.y)) + (bl(v6.y) + bl(v7.y)));
        acc.w += ((bh(v0.y) + bh(v1.y)) + (bh(v2.y) + bh(v3.y))) +
                 ((bh(v4.y) + bh(v5.y)) + (bh(v6.y) + bh(v7.y)));
    }
    for (; e + 4 <= end; e += 4) {
        int s0 = perm[e], s1 = perm[e + 1], s2 = perm[e + 2], s3 = perm[e + 3];
        uint2 v0 = xh[(size_t)s0 * 16 + c];
        uint2 v1 = xh[(size_t)s1 * 16 + c];
        uint2 v2 = xh[(size_t)s2 * 16 + c];
        uint2 v3 = xh[(size_t)s3 * 16 + c];
        acc.x += (bl(v0.x) + bl(v1.x)) + (bl(v2.x) + bl(v3.x));
        acc.y += (bh(v0.x) + bh(v1.x)) + (bh(v2.x) + bh(v3.x));
        acc.z += (bl(v0.y) + bl(v1.y)) + (bl(v2.y) + bl(v3.y));
        acc.w += (bh(v0.y) + bh(v1.y)) + (bh(v2.y) + bh(v3.y));
    }
    for (; e < end; ++e) {
        int s = perm[e];
        uint2 v = xh[(size_t)s * 16 + c];
        acc.x += bl(v.x); acc.y += bh(v.x); acc.z += bl(v.y); acc.w += bh(v.y);
    }
    out4[(size_t)node * 16 + c] = acc;
}

// h[n,128] = relu(x[n,64] @ W1[64,128] + b1); 16 rows/block (n % 16 == 0)
__global__ __launch_bounds__(256) void gemm1_relu(const float* __restrict__ x,
                                                  const float* __restrict__ W1,
                                                  const float* __restrict__ b1,
                                                  float* __restrict__ h, int n) {
    __shared__ float4 Ws[64][32];
    __shared__ float  xs[16][68];
    int t = threadIdx.x;
    const float4* W4 = reinterpret_cast<const float4*>(W1);
    for (int i = t; i < 64 * 32; i += 256) Ws[i >> 5][i & 31] = W4[i];

    int row0 = blockIdx.x * 16;
    const float4* x4 = reinterpret_cast<const float4*>(x + (size_t)row0 * 64);
    {
        float4 v = x4[t];
        int r = t >> 4, cc = t & 15;
        xs[r][cc * 4 + 0] = v.x;
        xs[r][cc * 4 + 1] = v.y;
        xs[r][cc * 4 + 2] = v.z;
        xs[r][cc * 4 + 3] = v.w;
    }
    __syncthreads();

    int r = t >> 4;
    int c = t & 15;
    float4 a0 = {0.f, 0.f, 0.f, 0.f}, a1 = {0.f, 0.f, 0.f, 0.f};
#pragma unroll
    for (int k = 0; k < 64; ++k) {
        float a = xs[r][k];
        float4 w0 = Ws[k][c];
        float4 w1 = Ws[k][c + 16];
        a0.x += a * w0.x; a0.y += a * w0.y; a0.z += a * w0.z; a0.w += a * w0.w;
        a1.x += a * w1.x; a1.y += a * w1.y; a1.z += a * w1.z; a1.w += a * w1.w;
    }
    const float4* b4 = reinterpret_cast<const float4*>(b1);
    float4 q0 = b4[c], q1 = b4[c + 16];
    a0.x = fmaxf(a0.x + q0.x, 0.f); a0.y = fmaxf(a0.y + q0.y, 0.f);
    a0.z = fmaxf(a0.z + q0.z, 0.f); a0.w = fmaxf(a0.w + q0.w, 0.f);
    a1.x = fmaxf(a1.x + q1.x, 0.f); a1.y = fmaxf(a1.y + q1.y, 0.f);
    a1.z = fmaxf(a1.z + q1.z, 0.f); a1.w = fmaxf(a1.w + q1.w, 0.f);
    float4* h4 = reinterpret_cast<float4*>(h) + ((size_t)row0 + r) * 32;
    h4[c] = a0;
    h4[c + 16] = a1;
}

// g = h[n,128] @ W2[128,64]; emits gh = bf16(g) and out = g + b2 (f32 self+bias)
__global__ __launch_bounds__(256) void gemm2(const float* __restrict__ h,
                                             const float* __restrict__ W2,
                                             const float* __restrict__ b2,
                                             uint2* __restrict__ gh,
                                             float4* __restrict__ out4, int n) {
    __shared__ float4 Ws[128][16];
    __shared__ float  xs[16][132];
    int t = threadIdx.x;
    const float4* W4 = reinterpret_cast<const float4*>(W2);
    for (int i = t; i < 128 * 16; i += 256) Ws[i >> 4][i & 15] = W4[i];
    int row0 = blockIdx.x * 16;
    const float4* x4 = reinterpret_cast<const float4*>(h + (size_t)row0 * 128);
    for (int i = t; i < 512; i += 256) {
        int r = i >> 5, c = i & 31;
        *reinterpret_cast<float4*>(&xs[r][c * 4]) = x4[i];
    }
    __syncthreads();

    int row = t >> 4;
    int cg  = t & 15;
    float4 acc = {0.f, 0.f, 0.f, 0.f};
#pragma unroll
    for (int k = 0; k < 128; ++k) {
        float a = xs[row][k];
        float4 w = Ws[k][cg];
        acc.x += a * w.x; acc.y += a * w.y; acc.z += a * w.z; acc.w += a * w.w;
    }
    size_t o = (size_t)(row0 + row) * 16 + cg;
    gh[o] = make_uint2(pk(acc.x, acc.y), pk(acc.z, acc.w));
    float4 bb = reinterpret_cast<const float4*>(b2)[cg];
    out4[o] = make_float4(acc.x + bb.x, acc.y + bb.y, acc.z + bb.z, acc.w + bb.w);
}

extern "C" void kernel_launch(void* const* d_in, const int* in_sizes, int n_in,
                              void* d_out, int out_size, void* d_ws, size_t ws_size,
                              hipStream_t stream) {
    const float* node_emb = (const float*)d_in[0];
    const float* W1 = (const float*)d_in[1];
    const float* b1 = (const float*)d_in[2];
    const float* W2 = (const float*)d_in[3];
    const float* b2 = (const float*)d_in[4];
    const int*   ei = (const int*)d_in[5];
    int n  = in_sizes[0] / 64;
    int ne = in_sizes[5] / 2;
    const int* src = ei;
    const int* dst = ei + ne;
    float* out = (float*)d_out;

    int nbins = (n + 255) >> 8;   // 391

    // workspace layout (aliases keep footprint ~84 MB):
    //   agg1 [n*64 f32]                ; gh aliases agg1 (agg1 dead after gemm1)
    //   h    [n*128 f32]               ; part aliases h[0..], xh aliases h[8MB..]
    //                                    (both consumed before gemm1 writes h)
    char* ws = (char*)d_ws;
    float* agg1 = (float*)ws;
    float* h    = (float*)(ws + (size_t)n * 64 * 4);
    unsigned* part = (unsigned*)h;                              // ne u32 (6.4 MB)
    uint2* xh   = (uint2*)((char*)h + (size_t)8 * 1024 * 1024); // n*16 uint2 (12.8 MB)
    uint2* gh   = (uint2*)agg1;                                 // n*16 uint2 (12.8 MB)
    char*  p    = ws + (size_t)n * 64 * 4 + (size_t)n * 128 * 4;
    int* off    = (int*)p;            p += (size_t)(n + 1) * 4;
    int* perm   = (int*)p;            p += (size_t)ne * 4;
    int* binCnt = (int*)p;            p += (size_t)(nbins + 1) * 4;
    int* binOff = (int*)p;            p += (size_t)(nbins + 1) * 4;
    int* binCur = (int*)p;            p += (size_t)(nbins + 1) * 4;

    int nblk = (ne + EPB - 1) / EPB;

    cvt_bf16<<<(n * 16 + 255) / 256, 256, 0, stream>>>((const float4*)node_emb, xh, n * 16);
    hipMemsetAsync(binCnt, 0, (size_t)nbins * 4, stream);
    bin_hist<<<nblk, 256, 0, stream>>>(dst, binCnt, ne, nbins);
    scan_bins<<<1, 512, 0, stream>>>(binCnt, binOff, binCur, off, nbins, n, ne);
    partition<<<nblk, 256, 0, stream>>>(src, dst, binCur, part, ne, nbins);
    bin_finalize<<<nbins, 256, 0, stream>>>(part, binOff, off, perm, n, nbins);

    gather64h<<<(n + 15) / 16, 256, 0, stream>>>(xh, (const float4*)node_emb, off, perm,
                                                 (float4*)agg1, n);
    gemm1_relu<<<(n + 15) / 16, 256, 0, stream>>>(agg1, W1, b1, h, n);
    gemm2<<<(n + 15) / 16, 256, 0, stream>>>(h, W2, b2, gh, (float4*)out, n);
    gather64h<<<(n + 15) / 16, 256, 0, stream>>>(gh, (const float4*)out, off, perm,
                                                 (float4*)out, n);
}

// Round 8
// 210.642 us; speedup vs baseline: 1.2586x; 1.0787x over previous
//
#include <hip/hip_runtime.h>

// GIN 2-layer forward — CSR counting sort + bf16 gather tables + reg-tiled GEMMs.
// Pipeline:
//   cvt_bf16: xh = bf16(node_emb)
//   bin_hist -> scan_bins -> partition -> bin_finalize   (CSR by dst)
//   agg1 = x + gather_bf16(xh)         [gather64h, 8-deep]
//   h    = relu(agg1 @ W1 + b1)        [gemm1_relu, 4x8 reg tile, h packed bf16]
//   gemm2: g = h @ W2 ; gh = bf16(g) ; out = g + b2      [4x4 reg tile]
//   out += gather_bf16(gh)             [gather64h]
// (W2 folded before aggregation-2: (A h + h) W2 + b2 = A(hW2) + hW2 + b2.)
// R5 lesson: don't fuse gather into GEMM (occupancy). R6: gather is cache-BW
// bound -> bf16 tables. R7: GEMMs were LDS-rate bound (4 FMA per 2 LDS reads);
// register tiling fixes the FMA:LDS ratio; bf16 h halves the h streams.

#define EPB 4096
#define CAP 6144

__device__ __forceinline__ unsigned short f2b(float f) {   // RNE f32->bf16
    unsigned u = __float_as_uint(f);
    return (unsigned short)((u + 0x7fffu + ((u >> 16) & 1u)) >> 16);
}
__device__ __forceinline__ unsigned pk(float a, float b) {
    return (unsigned)f2b(a) | ((unsigned)f2b(b) << 16);
}
__device__ __forceinline__ float bl(unsigned u) { return __uint_as_float(u << 16); }
__device__ __forceinline__ float bh(unsigned u) { return __uint_as_float(u & 0xffff0000u); }

__global__ void cvt_bf16(const float4* __restrict__ x4, uint2* __restrict__ xh, int n16) {
    int i = blockIdx.x * blockDim.x + threadIdx.x;
    if (i >= n16) return;
    float4 v = x4[i];
    xh[i] = make_uint2(pk(v.x, v.y), pk(v.z, v.w));
}

__global__ __launch_bounds__(256) void bin_hist(const int* __restrict__ dst,
                                                int* __restrict__ binCnt, int ne, int nbins) {
    __shared__ int h[512];
    int t = threadIdx.x;
    for (int i = t; i < nbins; i += 256) h[i] = 0;
    __syncthreads();
    int eb = blockIdx.x * EPB;
#pragma unroll
    for (int i = 0; i < 16; ++i) {
        int e = eb + t + i * 256;
        if (e < ne) atomicAdd(&h[dst[e] >> 8], 1);
    }
    __syncthreads();
    for (int i = t; i < nbins; i += 256) if (h[i]) atomicAdd(&binCnt[i], h[i]);
}

__global__ __launch_bounds__(512) void scan_bins(const int* __restrict__ binCnt,
                                                 int* __restrict__ binOff, int* __restrict__ binCur,
                                                 int* __restrict__ off, int nbins, int n, int ne) {
    __shared__ int s[512];
    int t = threadIdx.x;
    int v = (t < nbins) ? binCnt[t] : 0;
    s[t] = v;
    __syncthreads();
    for (int o = 1; o < 512; o <<= 1) {
        int u = (t >= o) ? s[t - o] : 0;
        __syncthreads();
        s[t] += u;
        __syncthreads();
    }
    if (t < nbins) { int b = s[t] - v; binOff[t] = b; binCur[t] = b; }
    if (t == 0) { binOff[nbins] = ne; off[n] = ne; }
}

__global__ __launch_bounds__(256) void partition(const int* __restrict__ src,
                                                 const int* __restrict__ dst,
                                                 int* __restrict__ binCur,
                                                 unsigned* __restrict__ part, int ne, int nbins) {
    __shared__ int h[512];
    __shared__ int base[512];
    int t = threadIdx.x;
    for (int i = t; i < nbins; i += 256) h[i] = 0;
    __syncthreads();
    int eb = blockIdx.x * EPB;
    int ss[16], ds[16];
#pragma unroll
    for (int i = 0; i < 16; ++i) {
        int e = eb + t + i * 256;
        if (e < ne) { ss[i] = src[e]; ds[i] = dst[e]; atomicAdd(&h[ds[i] >> 8], 1); }
        else ds[i] = -1;
    }
    __syncthreads();
    for (int i = t; i < nbins; i += 256) base[i] = h[i] ? atomicAdd(&binCur[i], h[i]) : 0;
    __syncthreads();
    for (int i = t; i < nbins; i += 256) h[i] = 0;
    __syncthreads();
#pragma unroll
    for (int i = 0; i < 16; ++i) {
        if (ds[i] >= 0) {
            int b = ds[i] >> 8;
            int p = atomicAdd(&h[b], 1);
            part[base[b] + p] = ((unsigned)ss[i] << 8) | (unsigned)(ds[i] & 255);
        }
    }
}

__global__ __launch_bounds__(256) void bin_finalize(const unsigned* __restrict__ part,
                                                    const int* __restrict__ binOff,
                                                    int* __restrict__ off, int* __restrict__ perm,
                                                    int n, int nbins) {
    __shared__ unsigned st[CAP];
    __shared__ int cnt[256], ex[256], cur[256];
    int b = blockIdx.x;
    int t = threadIdx.x;
    int e0 = binOff[b], e1 = binOff[b + 1];
    int m = e1 - e0;
    int nb0 = b << 8;
    int nn = min(256, n - nb0);
    cnt[t] = 0;
    __syncthreads();
    bool staged = (m <= CAP);
    if (staged) {
        for (int i = t; i < m; i += 256) { unsigned v = part[e0 + i]; st[i] = v; atomicAdd(&cnt[v & 255u], 1); }
    } else {
        for (int i = t; i < m; i += 256) { unsigned v = part[e0 + i]; atomicAdd(&cnt[v & 255u], 1); }
    }
    __syncthreads();
    int v = cnt[t];
    ex[t] = v;
    __syncthreads();
    for (int o = 1; o < 256; o <<= 1) {
        int u = (t >= o) ? ex[t - o] : 0;
        __syncthreads();
        ex[t] += u;
        __syncthreads();
    }
    int excl = ex[t] - v;
    if (t < nn) off[nb0 + t] = e0 + excl;
    cur[t] = excl;
    __syncthreads();
    if (staged) {
        for (int i = t; i < m; i += 256) {
            unsigned w = st[i];
            int p = atomicAdd(&cur[w & 255u], 1);
            perm[e0 + p] = (int)(w >> 8);
        }
    } else {
        for (int i = t; i < m; i += 256) {
            unsigned w = part[e0 + i];
            int p = atomicAdd(&cur[w & 255u], 1);
            perm[e0 + p] = (int)(w >> 8);
        }
    }
}

// out[i] = selfSrc[i] + sum_{e in CSR(i)} bf16_table[perm[e]]  (8-deep batch)
__global__ __launch_bounds__(256) void gather64h(const uint2* __restrict__ xh,
                                                 const float4* selfSrc,
                                                 const int* __restrict__ off,
                                                 const int* __restrict__ perm,
                                                 float4* out4, int n) {
    int t = threadIdx.x;
    int node = blockIdx.x * 16 + (t >> 4);
    int c = t & 15;
    if (node >= n) return;
    int beg = off[node], end = off[node + 1];
    float4 acc = selfSrc[(size_t)node * 16 + c];
    int e = beg;
    for (; e + 8 <= end; e += 8) {
        int s0 = perm[e],     s1 = perm[e + 1], s2 = perm[e + 2], s3 = perm[e + 3];
        int s4 = perm[e + 4], s5 = perm[e + 5], s6 = perm[e + 6], s7 = perm[e + 7];
        uint2 v0 = xh[(size_t)s0 * 16 + c];
        uint2 v1 = xh[(size_t)s1 * 16 + c];
        uint2 v2 = xh[(size_t)s2 * 16 + c];
        uint2 v3 = xh[(size_t)s3 * 16 + c];
        uint2 v4 = xh[(size_t)s4 * 16 + c];
        uint2 v5 = xh[(size_t)s5 * 16 + c];
        uint2 v6 = xh[(size_t)s6 * 16 + c];
        uint2 v7 = xh[(size_t)s7 * 16 + c];
        acc.x += ((bl(v0.x) + bl(v1.x)) + (bl(v2.x) + bl(v3.x))) +
                 ((bl(v4.x) + bl(v5.x)) + (bl(v6.x) + bl(v7.x)));
        acc.y += ((bh(v0.x) + bh(v1.x)) + (bh(v2.x) + bh(v3.x))) +
                 ((bh(v4.x) + bh(v5.x)) + (bh(v6.x) + bh(v7.x)));
        acc.z += ((bl(v0.y) + bl(v1.y)) + (bl(v2.y) + bl(v3.y))) +
                 ((bl(v4.y) + bl(v5.y)) + (bl(v6.y) + bl(v7.y)));
        acc.w += ((bh(v0.y) + bh(v1.y)) + (bh(v2.y) + bh(v3.y))) +
                 ((bh(v4.y) + bh(v5.y)) + (bh(v6.y) + bh(v7.y)));
    }
    for (; e + 4 <= end; e += 4) {
        int s0 = perm[e], s1 = perm[e + 1], s2 = perm[e + 2], s3 = perm[e + 3];
        uint2 v0 = xh[(size_t)s0 * 16 + c];
        uint2 v1 = xh[(size_t)s1 * 16 + c];
        uint2 v2 = xh[(size_t)s2 * 16 + c];
        uint2 v3 = xh[(size_t)s3 * 16 + c];
        acc.x += (bl(v0.x) + bl(v1.x)) + (bl(v2.x) + bl(v3.x));
        acc.y += (bh(v0.x) + bh(v1.x)) + (bh(v2.x) + bh(v3.x));
        acc.z += (bl(v0.y) + bl(v1.y)) + (bl(v2.y) + bl(v3.y));
        acc.w += (bh(v0.y) + bh(v1.y)) + (bh(v2.y) + bh(v3.y));
    }
    for (; e < end; ++e) {
        int s = perm[e];
        uint2 v = xh[(size_t)s * 16 + c];
        acc.x += bl(v.x); acc.y += bh(v.x); acc.z += bl(v.y); acc.w += bh(v.y);
    }
    out4[(size_t)node * 16 + c] = acc;
}

// h[n,128] = relu(x[n,64] @ W1 + b1), h packed bf16 (u32 = col pair).
// 64 rows/block; thread (rg=t>>4, cg=t&15): rows 4rg..+3, f4 col-groups {cg, cg+16}.
// Per k: 4 broadcast b32 (a) + 2 b128 (w) feed 32 FMAs -> VALU-bound.
__global__ __launch_bounds__(256) void gemm1_relu(const float* __restrict__ x,
                                                  const float* __restrict__ W1,
                                                  const float* __restrict__ b1,
                                                  uint2* __restrict__ h, int n) {
    __shared__ float4 Ws[64][32];   // 32 KiB
    __shared__ float  xs[64][65];   // 16.25 KiB, odd stride -> <=2-way conflicts
    int t = threadIdx.x;
    const float4* W4 = reinterpret_cast<const float4*>(W1);
    for (int i = t; i < 64 * 32; i += 256) Ws[i >> 5][i & 31] = W4[i];
    int row0 = blockIdx.x * 64;
    for (int i = t; i < 1024; i += 256) {        // 64 rows x 16 f4
        int r = i >> 4, c = i & 15;
        if (row0 + r < n) {
            float4 v = reinterpret_cast<const float4*>(x)[(size_t)(row0 + r) * 16 + c];
            xs[r][c * 4 + 0] = v.x; xs[r][c * 4 + 1] = v.y;
            xs[r][c * 4 + 2] = v.z; xs[r][c * 4 + 3] = v.w;
        }
    }
    __syncthreads();

    int rg = t >> 4, cg = t & 15;
    float4 a0[4], a1[4];
#pragma unroll
    for (int r = 0; r < 4; ++r) { a0[r] = make_float4(0.f,0.f,0.f,0.f); a1[r] = make_float4(0.f,0.f,0.f,0.f); }
#pragma unroll 4
    for (int k = 0; k < 64; ++k) {
        float4 w0 = Ws[k][cg];
        float4 w1 = Ws[k][cg + 16];
#pragma unroll
        for (int r = 0; r < 4; ++r) {
            float a = xs[4 * rg + r][k];
            a0[r].x += a * w0.x; a0[r].y += a * w0.y; a0[r].z += a * w0.z; a0[r].w += a * w0.w;
            a1[r].x += a * w1.x; a1[r].y += a * w1.y; a1[r].z += a * w1.z; a1[r].w += a * w1.w;
        }
    }
    const float4* b4 = reinterpret_cast<const float4*>(b1);
    float4 q0 = b4[cg], q1 = b4[cg + 16];
#pragma unroll
    for (int r = 0; r < 4; ++r) {
        int row = row0 + 4 * rg + r;
        if (row >= n) break;
        float4 m0, m1;
        m0.x = fmaxf(a0[r].x + q0.x, 0.f); m0.y = fmaxf(a0[r].y + q0.y, 0.f);
        m0.z = fmaxf(a0[r].z + q0.z, 0.f); m0.w = fmaxf(a0[r].w + q0.w, 0.f);
        m1.x = fmaxf(a1[r].x + q1.x, 0.f); m1.y = fmaxf(a1[r].y + q1.y, 0.f);
        m1.z = fmaxf(a1[r].z + q1.z, 0.f); m1.w = fmaxf(a1[r].w + q1.w, 0.f);
        size_t base = (size_t)row * 32;   // 128 bf16 = 32 uint2 per row
        h[base + cg]      = make_uint2(pk(m0.x, m0.y), pk(m0.z, m0.w));
        h[base + cg + 16] = make_uint2(pk(m1.x, m1.y), pk(m1.z, m1.w));
    }
}

// g = h[n,128(bf16)] @ W2[128,64]; gh = bf16(g); out = g + b2 (f32).
// 64 rows/block; thread (rg,cg): rows 4rg..+3, f4 col-group cg. K staged in
// two 64-wide phases (unpack bf16 once at staging).
__global__ __launch_bounds__(256) void gemm2(const unsigned* __restrict__ h,
                                             const float* __restrict__ W2,
                                             const float* __restrict__ b2,
                                             uint2* __restrict__ gh,
                                             float4* __restrict__ out4, int n) {
    __shared__ float4 Ws[128][16];  // 32 KiB
    __shared__ float  hs[64][65];   // 16.25 KiB
    int t = threadIdx.x;
    const float4* W4 = reinterpret_cast<const float4*>(W2);
    for (int i = t; i < 128 * 16; i += 256) Ws[i >> 4][i & 15] = W4[i];
    int row0 = blockIdx.x * 64;
    int rg = t >> 4, cg = t & 15;
    float4 acc[4];
#pragma unroll
    for (int r = 0; r < 4; ++r) acc[r] = make_float4(0.f,0.f,0.f,0.f);

    for (int kt = 0; kt < 2; ++kt) {
        __syncthreads();   // protect previous phase (and Ws on first iter)
        for (int i = t; i < 2048; i += 256) {    // 64 rows x 32 u32 (=64 bf16)
            int r = i >> 5, c = i & 31;
            if (row0 + r < n) {
                unsigned u = h[(size_t)(row0 + r) * 64 + kt * 32 + c];
                hs[r][c * 2]     = bl(u);
                hs[r][c * 2 + 1] = bh(u);
            }
        }
        __syncthreads();
#pragma unroll 4
        for (int kk = 0; kk < 64; ++kk) {
            float4 w = Ws[kt * 64 + kk][cg];
#pragma unroll
            for (int r = 0; r < 4; ++r) {
                float a = hs[4 * rg + r][kk];
                acc[r].x += a * w.x; acc[r].y += a * w.y;
                acc[r].z += a * w.z; acc[r].w += a * w.w;
            }
        }
    }
    float4 bb = reinterpret_cast<const float4*>(b2)[cg];
#pragma unroll
    for (int r = 0; r < 4; ++r) {
        int row = row0 + 4 * rg + r;
        if (row >= n) break;
        size_t o = (size_t)row * 16 + cg;
        gh[o] = make_uint2(pk(acc[r].x, acc[r].y), pk(acc[r].z, acc[r].w));
        out4[o] = make_float4(acc[r].x + bb.x, acc[r].y + bb.y,
                              acc[r].z + bb.z, acc[r].w + bb.w);
    }
}

extern "C" void kernel_launch(void* const* d_in, const int* in_sizes, int n_in,
                              void* d_out, int out_size, void* d_ws, size_t ws_size,
                              hipStream_t stream) {
    const float* node_emb = (const float*)d_in[0];
    const float* W1 = (const float*)d_in[1];
    const float* b1 = (const float*)d_in[2];
    const float* W2 = (const float*)d_in[3];
    const float* b2 = (const float*)d_in[4];
    const int*   ei = (const int*)d_in[5];
    int n  = in_sizes[0] / 64;
    int ne = in_sizes[5] / 2;
    const int* src = ei;
    const int* dst = ei + ne;
    float* out = (float*)d_out;

    int nbins = (n + 255) >> 8;   // 391

    // workspace layout (same offsets as R7; aliases documented):
    //   agg1 [n*64 f32, 25.6MB]  ; gh aliases agg1 (agg1 dead after gemm1)
    //   hbuf [25.6MB used of 51.2MB slot] ; part aliases hbuf[0..6.4MB],
    //        xh aliases hbuf[8MB..20.8MB] (both consumed before gemm1 writes h)
    char* ws = (char*)d_ws;
    float* agg1 = (float*)ws;
    char*  hslot = ws + (size_t)n * 64 * 4;
    uint2* h    = (uint2*)hslot;                                 // n*32 uint2 (25.6 MB)
    unsigned* part = (unsigned*)hslot;                           // ne u32 (6.4 MB)
    uint2* xh   = (uint2*)(hslot + (size_t)8 * 1024 * 1024 + (size_t)26 * 1024 * 1024);
    // ^ xh placed past h's 25.6MB so it survives gemm1's h writes? NO — xh is
    //   dead after gather1 (before gemm1), so it may alias h. Keep it simple:
    uint2* gh   = (uint2*)agg1;
    char*  p    = ws + (size_t)n * 64 * 4 + (size_t)n * 128 * 4;
    int* off    = (int*)p;            p += (size_t)(n + 1) * 4;
    int* perm   = (int*)p;            p += (size_t)ne * 4;
    int* binCnt = (int*)p;            p += (size_t)(nbins + 1) * 4;
    int* binOff = (int*)p;            p += (size_t)(nbins + 1) * 4;
    int* binCur = (int*)p;            p += (size_t)(nbins + 1) * 4;
    xh = (uint2*)(hslot + (size_t)8 * 1024 * 1024);              // as in R7

    int nblk = (ne + EPB - 1) / EPB;

    cvt_bf16<<<(n * 16 + 255) / 256, 256, 0, stream>>>((const float4*)node_emb, xh, n * 16);
    hipMemsetAsync(binCnt, 0, (size_t)nbins * 4, stream);
    bin_hist<<<nblk, 256, 0, stream>>>(dst, binCnt, ne, nbins);
    scan_bins<<<1, 512, 0, stream>>>(binCnt, binOff, binCur, off, nbins, n, ne);
    partition<<<nblk, 256, 0, stream>>>(src, dst, binCur, part, ne, nbins);
    bin_finalize<<<nbins, 256, 0, stream>>>(part, binOff, off, perm, n, nbins);

    gather64h<<<(n + 15) / 16, 256, 0, stream>>>(xh, (const float4*)node_emb, off, perm,
                                                 (float4*)agg1, n);
    gemm1_relu<<<(n + 63) / 64, 256, 0, stream>>>(agg1, W1, b1, h, n);
    gemm2<<<(n + 63) / 64, 256, 0, stream>>>((const unsigned*)h, W2, b2, gh, (float4*)out, n);
    gather64h<<<(n + 15) / 16, 256, 0, stream>>>(gh, (const float4*)out, off, perm,
                                                 (float4*)out, n);
}